// Round 16
// baseline (1280.103 us; speedup 1.0000x reference)
//
#include <hip/hip_runtime.h>
#include <hip/hip_bf16.h>

#define T_STEPS 2048
#define BATCH   1024
#define NUNITS  128
#define ROWS    4
#define LOG2E   1.4426950408889634f

typedef __attribute__((ext_vector_type(4))) float  f32x4;
typedef __attribute__((ext_vector_type(2))) int    i32x2;
typedef __attribute__((ext_vector_type(4))) int    int4v;

__device__ __forceinline__ float sigm_pre(float xs) {
    return __builtin_amdgcn_rcpf(1.0f + __builtin_amdgcn_exp2f(-xs));
}
__device__ __forceinline__ float tanh_pre(float xs) {
    return fmaf(-2.0f, __builtin_amdgcn_rcpf(1.0f + __builtin_amdgcn_exp2f(xs)), 1.0f);
}
// lanes 0-31 = a[self], lanes 32-63 = b[lane-32]  (verified R7); int version
__device__ __forceinline__ int swap_lo_i(int a, int b) {
    i32x2 r = __builtin_amdgcn_permlane32_swap(a, b, false, false);
    return r[0];
}
// 16-lane-granular analog (verified R15): (lane&16)==0 -> a[self], ==1 -> b[lane-16]
__device__ __forceinline__ int swap16_lo_i(int a, int b) {
    i32x2 r = __builtin_amdgcn_permlane16_swap(a, b, false, false);
    return r[0];
}

// ---------------- embedding pre-pass: e[t][b][0..23] = rint(sigmoid(.)*127) as i8,
// bytes 24-31 zero pad (verified R13)
__global__ __launch_bounds__(256) void emb_kernel(const float* __restrict__ x,
                                                  const float* __restrict__ Wemb,
                                                  const float* __restrict__ bemb,
                                                  uchar* __restrict__ e_out) {
    int g = blockIdx.x * 256 + threadIdx.x;   // g = t*1024 + b
    int t = g >> 10;
    int b = g & 1023;
    const float* xr = x + ((size_t)b * T_STEPS + t) * 64;

    float4 xv[16];
#pragma unroll
    for (int i = 0; i < 16; i++) xv[i] = ((const float4*)xr)[i];

    float acc[24];
#pragma unroll
    for (int j = 0; j < 24; j++) acc[j] = bemb[j];

#pragma unroll
    for (int d = 0; d < 64; d++) {
        float xs = ((const float*)xv)[d];
#pragma unroll
        for (int j = 0; j < 24; j++) acc[j] = fmaf(xs, Wemb[d * 24 + j], acc[j]);
    }

    uint outp[8] = {0, 0, 0, 0, 0, 0, 0, 0};
#pragma unroll
    for (int j = 0; j < 24; j++) {
        float s = __builtin_amdgcn_rcpf(1.0f + __builtin_amdgcn_exp2f(-LOG2E * acc[j]));
        int q = (int)__builtin_rintf(s * 127.0f);
        outp[j >> 2] |= (uint)(q & 255) << (8 * (j & 3));
    }
    uint4* dst = (uint4*)(e_out + (size_t)g * 32);
    dst[0] = ((const uint4*)outp)[0];
    dst[1] = ((const uint4*)outp)[1];
}

// ---------------- recurrent kernel: 256 blocks x 512 threads (8 waves), 4 rows/block.
// All-INT8 GEMM, 1 valid cell/thread, all-VALU compaction (verified R15). NEW vs R15:
//  (a) wave-staggered phase order: odd waves issue z ds_reads BEFORE their e-MFMAs,
//      even waves after -> spreads the post-barrier 16x ds_read_b128 LDS burst;
//  (b) magic-number h-quantize: fmaf(h,127,1.5*2^23) -> RNE int in mantissa low
//      byte, stored directly by ds_write_b8 (replaces mul+rndne+cvt).
__global__ __launch_bounds__(512, 1) void lstm_kernel(
    const uchar* __restrict__ e_ws,
    const float* __restrict__ Wf, const float* __restrict__ bf_,
    const float* __restrict__ Wi, const float* __restrict__ bi_,
    const float* __restrict__ Wg, const float* __restrict__ bg_,
    const float* __restrict__ Wo, const float* __restrict__ bo_,
    const float* __restrict__ Wout, const float* __restrict__ bout,
    float* __restrict__ out) {
    __shared__ __align__(16) char zq[2][2][4][16][16];   // [P][ks2][kg4][row16][16B] = 4 KiB

    const int tid  = threadIdx.x;
    const int lane = tid & 63;
    const int wv   = tid >> 6;      // 0..7 -> unit tile [16wv,16wv+16)
    const int l15  = lane & 15;
    const int kg   = lane >> 4;     // 0..3 (A k-group; also this thread's OWNED ROW)
    const int r0   = blockIdx.x * ROWS;

    const float* Wp[4] = {Wf, Wi, Wg, Wo};
    const float* Bp[4] = {bf_, bi_, bg_, bo_};
    const float gsc[4] = {LOG2E, LOG2E, 2.0f * LOG2E, LOG2E};
    const int ucol = wv * 16 + l15;   // this lane's unit (D n-index)

    // ---- weights: per-(gate,unit) scaled int8 over all 152 K-rows, packed [gt][ks3]
    int4v wq[4][3];
    float fct[4], biasv[4];
#pragma unroll
    for (int gt = 0; gt < 4; gt++) {
        float amax = 1e-20f;
        for (int k = 0; k < 152; k++) {
            float v = (k < 128) ? Wp[gt][(24 + k) * NUNITS + ucol]
                                : Wp[gt][(k - 128) * NUNITS + ucol];
            amax = fmaxf(amax, fabsf(v * gsc[gt]));
        }
        float isq = 127.0f / amax;
        fct[gt] = amax * (1.0f / 16129.0f);   // s_w/127: i32 -> pre-activation scale
#pragma unroll
        for (int ks = 0; ks < 3; ks++) {
#pragma unroll
            for (int w = 0; w < 4; w++) {
                int word = 0;
#pragma unroll
                for (int b = 0; b < 4; b++) {
                    int k = ks * 64 + kg * 16 + w * 4 + b;
                    float v = 0.0f;
                    if (k < 128) v = Wp[gt][(24 + k) * NUNITS + ucol] * gsc[gt];
                    else if (k < 152) v = Wp[gt][(k - 128) * NUNITS + ucol] * gsc[gt];
                    int q = (int)__builtin_rintf(v * isq);
                    word |= (q & 255) << (8 * b);
                }
                wq[gt][ks][w] = word;
            }
        }
        biasv[gt] = Bp[gt][ucol] * gsc[gt];
    }
    const int4v zeroi = {0, 0, 0, 0};

    // zero both z buffers (h0 = 0; rows 4-15 stay zero forever)
    for (int i = tid; i < (int)(sizeof(zq) / 4); i += 512) ((int*)zq)[i] = 0;

    // LDS addrs: A-frag read 16B (k = ks*64 + kg*16 + j); write 1 i8 cell (row=kg)
    const char* zrd = &zq[0][0][kg][l15][0];            // + P*2048 + ks*1024
    char* zwr = &zq[0][ucol >> 6][(ucol >> 4) & 3][kg][ucol & 15];

    // ---- e ring, depth 2: lanes (kg<2, l15<4) hold row l15, bytes kg*16..+16
    const uchar* elbase = e_ws + ((size_t)(r0 + (l15 & 3)) * 32 + kg * 16);
    const bool eload = (kg < 2) && (l15 < 4);
    int4v e0 = zeroi, e1 = zeroi;
    if (eload) {
        e0 = *(const int4v*)(const void*)(elbase);
        e1 = *(const int4v*)(const void*)(elbase + 32768);   // t=1 (1024*32 B/step)
    }
    const uchar* eptr = elbase + 2 * 32768;   // marching prefetch ptr: next load = e(2)

    __syncthreads();

    float c0 = 0.0f;
    const bool zfirst = (wv & 1);   // wave-uniform stagger

    auto STEP = [&](int P, int4v& ecur) {
        const char* zb = zrd + P * 2048;
        int4v acc[4], z0, z1;

        if (zfirst) {
            // odd waves: issue LDS reads first, e-MFMAs fill the latency
            z0 = *(const int4v*)(const void*)(zb);
            z1 = *(const int4v*)(const void*)(zb + 1024);
#pragma unroll
            for (int gt = 0; gt < 4; gt++)
                acc[gt] = __builtin_amdgcn_mfma_i32_16x16x64_i8(ecur, wq[gt][2], zeroi, 0, 0, 0);
        } else {
            // even waves: e-MFMAs first, LDS reads issue behind them
#pragma unroll
            for (int gt = 0; gt < 4; gt++)
                acc[gt] = __builtin_amdgcn_mfma_i32_16x16x64_i8(ecur, wq[gt][2], zeroi, 0, 0, 0);
            z0 = *(const int4v*)(const void*)(zb);
            z1 = *(const int4v*)(const void*)(zb + 1024);
        }

#pragma unroll
        for (int gt = 0; gt < 4; gt++)
            acc[gt] = __builtin_amdgcn_mfma_i32_16x16x64_i8(z0, wq[gt][0], acc[gt], 0, 0, 0);
#pragma unroll
        for (int gt = 0; gt < 4; gt++)
            acc[gt] = __builtin_amdgcn_mfma_i32_16x16x64_i8(z1, wq[gt][1], acc[gt], 0, 0, 0);

        // refill ering with e(t+2): marching pointer (<=2-step overrun, never consumed)
        if (eload) ecur = *(const int4v*)(const void*)(eptr);
        eptr += 32768;

        // full compaction (i32, bit-exact, all-VALU): lane-group kg -> row kg
        float g[4];
#pragma unroll
        for (int gt = 0; gt < 4; gt++) {
            int a0 = swap_lo_i(acc[gt][0], acc[gt][2]);    // l0-15:r0, l32-47:r2
            int a1 = swap_lo_i(acc[gt][1], acc[gt][3]);    // l0-15:r1, l32-47:r3
            int sel = swap16_lo_i(a0, a1);
            g[gt] = fmaf((float)sel, fct[gt], biasv[gt]);
        }

        float fg = sigm_pre(g[0]);
        float ig = sigm_pre(g[1]);
        float gg = tanh_pre(g[2]);
        float og = sigm_pre(g[3]);
        c0 = fmaf(c0, fg, ig * gg);
        float h0 = tanh_pre(2.0f * LOG2E * c0) * og;

        // magic-number quantize: RNE int8 lands in mantissa low byte; b8 store
        // writes register bits [7:0] directly (|h|<1 -> q in [-127,127])
        float fq = fmaf(h0, 127.0f, 12582912.0f);   // 1.5 * 2^23
        *(zwr + ((P ^ 1) * 2048)) = (char)(__builtin_bit_cast(uint, fq) & 0xFF);

        asm volatile("s_waitcnt lgkmcnt(0)" ::: "memory");
        __builtin_amdgcn_s_barrier();
        __builtin_amdgcn_sched_barrier(0);
    };

    for (int t = 0; t < T_STEPS; t += 2) {
        STEP(0, e0);
        STEP(1, e1);
    }

    // h_last (i8) in buffer 0, rows 0-3
    if (tid < ROWS) {
        float s2 = 0.0f;
#pragma unroll
        for (int k = 0; k < NUNITS; k++)
            s2 += (float)zq[0][k >> 6][(k >> 4) & 3][tid][k & 15] * Wout[k];
        float s = s2 * (1.0f / 127.0f) + bout[0];
        out[r0 + tid] = __builtin_amdgcn_rcpf(1.0f + __builtin_amdgcn_exp2f(-LOG2E * s));
    }
}

extern "C" void kernel_launch(void* const* d_in, const int* in_sizes, int n_in,
                              void* d_out, int out_size, void* d_ws, size_t ws_size,
                              hipStream_t stream) {
    const float* x     = (const float*)d_in[0];
    const float* Wemb  = (const float*)d_in[1];
    const float* bemb  = (const float*)d_in[2];
    const float* Wf    = (const float*)d_in[3];
    const float* bf_   = (const float*)d_in[4];
    const float* Wi    = (const float*)d_in[5];
    const float* bi_   = (const float*)d_in[6];
    const float* Wg    = (const float*)d_in[7];
    const float* bg_   = (const float*)d_in[8];
    const float* Wo    = (const float*)d_in[9];
    const float* bo_   = (const float*)d_in[10];
    const float* Wout  = (const float*)d_in[11];
    const float* bout  = (const float*)d_in[12];
    float* out = (float*)d_out;
    uchar* e_ws = (uchar*)d_ws;   // [T][B][32] i8, 64 MB (+<=64KB overrun reads)

    int nrows = BATCH * T_STEPS;
    emb_kernel<<<nrows / 256, 256, 0, stream>>>(x, Wemb, bemb, e_ws);
    lstm_kernel<<<BATCH / ROWS, 512, 0, stream>>>(e_ws, Wf, bf_, Wi, bi_, Wg, bg_,
                                                  Wo, bo_, Wout, bout, out);
}